// Round 1
// baseline (54.281 us; speedup 1.0000x reference)
//
#include <hip/hip_runtime.h>

typedef __bf16 bf16x8 __attribute__((ext_vector_type(8)));
typedef float  f32x4  __attribute__((ext_vector_type(4)));

#define NI 256
#define NT 256
#define NL 32
#define NE 128
#define HW 49

// Block: 256 threads = 4 waves; wave w owns image ib*4+w.
// Grid: 512 = (I/4=64 image groups) x (T/32=8 text chunks).
// Per wave: A-frags (one image, 64x128 bf16) held in VGPRs for the whole
// block; texts staged 4-at-a-time in XOR-swizzled LDS shared by all 4 waves.
__global__ __launch_bounds__(256, 2)
void clip_match_kernel(const float* __restrict__ img,
                       const float* __restrict__ txt,
                       const int* __restrict__ tlen,
                       const float* __restrict__ nlt,
                       float* __restrict__ out)
{
    const int tid  = threadIdx.x;
    const int wave = tid >> 6;
    const int lane = tid & 63;
    const int lo   = lane & 15;
    const int hi   = lane >> 4;

    const int tb = blockIdx.x & 7;    // text chunk (32 texts)
    const int ib = blockIdx.x >> 3;   // image group (4 images)
    const int img_i = ib * 4 + wave;

    const float scale = expf(nlt[0]);

    // ---- A fragments: image img_i as [64(pad from 49) x 128] bf16 ----
    // lane holds A[m = mf*16+lo, k = ks*32 + hi*8 + j]; A[m,k] = img[i,e=k,hw=m]
    bf16x8 afrag[4][4];
    {
        const float* __restrict__ pi = img + (size_t)img_i * (NE * HW);
        #pragma unroll
        for (int mf = 0; mf < 4; ++mf) {
            int m  = mf * 16 + lo;
            int mc = m < HW ? m : HW - 1;   // clamp; pad rows masked in reduce
            #pragma unroll
            for (int ks = 0; ks < 4; ++ks) {
                int kb = ks * 32 + hi * 8;
                bf16x8 a;
                #pragma unroll
                for (int j = 0; j < 8; ++j)
                    a[j] = (__bf16)pi[(kb + j) * HW + mc];
                afrag[mf][ks] = a;
            }
        }
    }

    __shared__ __align__(16) __bf16 lds[4 * NL * NE];  // 4 texts, 32 KiB

    const float* __restrict__ tsrc0 = txt + (size_t)tb * 32 * NL * NE;

    for (int tg = 0; tg < 8; ++tg) {
        __syncthreads();
        // ---- stage 4 texts -> LDS bf16, row-XOR-swizzle (row&7)<<4 ----
        {
            const float* __restrict__ src = tsrc0 + (size_t)tg * 4 * NL * NE;
            #pragma unroll
            for (int r = 0; r < 8; ++r) {
                int c    = tid + 256 * r;        // chunk 0..2047
                int ts   = c >> 9;               // text-in-group
                int word = (c >> 4) & 31;        // l
                int ec   = c & 15;               // 8-float chunk along e
                const float* p = src + ((ts * NL + word) * NE + ec * 8);
                float4 f0 = *(const float4*)p;
                float4 f1 = *(const float4*)(p + 4);
                union { __bf16 b[8]; int4 v; } u;
                u.b[0] = (__bf16)f0.x; u.b[1] = (__bf16)f0.y;
                u.b[2] = (__bf16)f0.z; u.b[3] = (__bf16)f0.w;
                u.b[4] = (__bf16)f1.x; u.b[5] = (__bf16)f1.y;
                u.b[6] = (__bf16)f1.z; u.b[7] = (__bf16)f1.w;
                int row = ts * NL + word;
                int off = row * 256 + ec * 16;
                off ^= (word & 7) << 4;
                *(int4*)((char*)lds + off) = u.v;
            }
        }
        __syncthreads();

        #pragma unroll 1
        for (int ts = 0; ts < 4; ++ts) {
            const int t = tb * 32 + tg * 4 + ts;
            // ---- B fragments: lane holds B[k = ks*32+hi*8+j, col = nf*16+lo]
            //      = txt[t, l=col, e=k]  (same k-map as A -> permutation-safe)
            bf16x8 bfrag[2][4];
            #pragma unroll
            for (int nf = 0; nf < 2; ++nf) {
                int word = nf * 16 + lo;
                int row  = ts * NL + word;
                #pragma unroll
                for (int ks = 0; ks < 4; ++ks) {
                    int off = row * 256 + (ks * 32 + hi * 8) * 2;
                    off ^= (word & 7) << 4;
                    bfrag[nf][ks] = *(const bf16x8*)((const char*)lds + off);
                }
            }
            f32x4 acc[4][2];
            #pragma unroll
            for (int mf = 0; mf < 4; ++mf)
                #pragma unroll
                for (int nf = 0; nf < 2; ++nf)
                    acc[mf][nf] = (f32x4){0.f, 0.f, 0.f, 0.f};
            #pragma unroll
            for (int ks = 0; ks < 4; ++ks)
                #pragma unroll
                for (int mf = 0; mf < 4; ++mf)
                    #pragma unroll
                    for (int nf = 0; nf < 2; ++nf)
                        acc[mf][nf] = __builtin_amdgcn_mfma_f32_16x16x32_bf16(
                            afrag[mf][ks], bfrag[nf][ks], acc[mf][nf], 0, 0, 0);

            // ---- reduce: max over valid rows (hw), sum over 32 cols (l) ----
            // C/D layout (verified m89/m91): col = lane&15, row = hi*4 + reg
            float cm0 = -3.0e38f, cm1 = -3.0e38f;
            #pragma unroll
            for (int mf = 0; mf < 4; ++mf)
                #pragma unroll
                for (int r = 0; r < 4; ++r) {
                    int m = mf * 16 + hi * 4 + r;
                    if (m < HW) {
                        cm0 = fmaxf(cm0, acc[mf][0][r]);
                        cm1 = fmaxf(cm1, acc[mf][1][r]);
                    }
                }
            cm0 = fmaxf(cm0, __shfl_xor(cm0, 16));
            cm0 = fmaxf(cm0, __shfl_xor(cm0, 32));
            cm1 = fmaxf(cm1, __shfl_xor(cm1, 16));
            cm1 = fmaxf(cm1, __shfl_xor(cm1, 32));
            float s = cm0 + cm1;                 // cols lo and lo+16
            s += __shfl_xor(s, 1);
            s += __shfl_xor(s, 2);
            s += __shfl_xor(s, 4);
            s += __shfl_xor(s, 8);               // Sum over all 32 cols
            if (lane == 0) {
                float v = s * scale / (float)tlen[t];
                out[img_i * NT + t] = v;             // logits_per_image[i,t]
                out[NI * NT + t * NI + img_i] = v;   // logits_per_text[t,i]
            }
        }
    }
}

extern "C" void kernel_launch(void* const* d_in, const int* in_sizes, int n_in,
                              void* d_out, int out_size, void* d_ws, size_t ws_size,
                              hipStream_t stream)
{
    const float* img  = (const float*)d_in[0];
    const float* txt  = (const float*)d_in[1];
    const int*   tlen = (const int*)d_in[2];
    const float* nlt  = (const float*)d_in[3];
    float* out = (float*)d_out;
    clip_match_kernel<<<dim3(512), dim3(256), 0, stream>>>(img, txt, tlen, nlt, out);
}

// Round 2
// 49.714 us; speedup vs baseline: 1.0919x; 1.0919x over previous
//
#include <hip/hip_runtime.h>

typedef __bf16 bf16x8 __attribute__((ext_vector_type(8)));
typedef float  f32x16 __attribute__((ext_vector_type(16)));

#define NI 256
#define NT 256
#define NL 32
#define NE 128
#define HW 49

// Block: 256 threads = 4 waves; wave w owns image ib*4+w (M = 64 pad of 49 hw).
// Grid: 1024 = 64 image-groups x 16 text-chunks (16 texts each).
// MFMA: 32x32x16 bf16. Per text: 8 ds_read_b128 (B), 16 MFMA, short reduce.
__global__ __launch_bounds__(256, 3)
void clip_match_kernel(const float* __restrict__ img,
                       const float* __restrict__ txt,
                       const int* __restrict__ tlen,
                       const float* __restrict__ nlt,
                       float* __restrict__ out)
{
    const int tid  = threadIdx.x;
    const int wave = tid >> 6;
    const int lane = tid & 63;
    const int ml   = lane & 31;   // m (A rows) / n (B cols) lane index
    const int h    = lane >> 5;   // k-half

    const int tb = blockIdx.x & 15;   // text chunk (16 texts)
    const int ib = blockIdx.x >> 4;   // image group (4 images)
    const int img_i = ib * 4 + wave;

    const float scale = expf(nlt[0]);

    // ---- A fragments: image img_i as [64(pad 49) x 128] bf16, 64 VGPRs ----
    // lane holds A[m = mf*32 + ml, k = ks*16 + h*8 + j]; A[m,k] = img[i,e=k,hw=m]
    bf16x8 afrag[2][8];
    {
        const float* __restrict__ pi = img + (size_t)img_i * (NE * HW);
        #pragma unroll
        for (int mf = 0; mf < 2; ++mf) {
            int m  = mf * 32 + ml;
            int mc = m < HW ? m : HW - 1;   // clamp; pad rows masked in reduce
            #pragma unroll
            for (int ks = 0; ks < 8; ++ks) {
                int kb = ks * 16 + h * 8;
                bf16x8 a;
                #pragma unroll
                for (int j = 0; j < 8; ++j)
                    a[j] = (__bf16)pi[(kb + j) * HW + mc];
                afrag[mf][ks] = a;
            }
        }
    }

    __shared__ __align__(16) __bf16 lds[4 * NL * NE];  // 4 texts, 32 KiB

    const float* __restrict__ tsrc0 = txt + (size_t)tb * 16 * NL * NE;

    for (int tg = 0; tg < 4; ++tg) {
        __syncthreads();
        // ---- stage 4 texts -> LDS bf16, row-XOR-swizzle (row&7)<<4 ----
        {
            const float* __restrict__ src = tsrc0 + (size_t)tg * 4 * NL * NE;
            #pragma unroll
            for (int r = 0; r < 8; ++r) {
                int c    = tid + 256 * r;        // chunk 0..2047
                int ts   = c >> 9;               // text-in-group
                int word = (c >> 4) & 31;        // l
                int ec   = c & 15;               // 8-float chunk along e
                const float* p = src + ((ts * NL + word) * NE + ec * 8);
                float4 f0 = *(const float4*)p;
                float4 f1 = *(const float4*)(p + 4);
                union { __bf16 b[8]; int4 v; } u;
                u.b[0] = (__bf16)f0.x; u.b[1] = (__bf16)f0.y;
                u.b[2] = (__bf16)f0.z; u.b[3] = (__bf16)f0.w;
                u.b[4] = (__bf16)f1.x; u.b[5] = (__bf16)f1.y;
                u.b[6] = (__bf16)f1.z; u.b[7] = (__bf16)f1.w;
                int row = ts * NL + word;
                int off = row * 256 + ec * 16;
                off ^= (word & 7) << 4;
                *(int4*)((char*)lds + off) = u.v;
            }
        }
        __syncthreads();

        #pragma unroll 1
        for (int ts = 0; ts < 4; ++ts) {
            const int t = tb * 16 + tg * 4 + ts;
            const float rl = scale / (float)tlen[t];   // issued early, used last
            // ---- B fragments: lane holds B[k = ks*16+h*8+j, n = ml]
            //      = txt[t, l=ml, e=k]  (same k-map as A -> permutation-safe)
            bf16x8 bfrag[8];
            {
                int row = ts * NL + ml;
                int sw  = (row & 7) << 4;
                #pragma unroll
                for (int ks = 0; ks < 8; ++ks) {
                    int off = (row * 256 + ks * 32 + h * 16) ^ sw;
                    bfrag[ks] = *(const bf16x8*)((const char*)lds + off);
                }
            }
            f32x16 acc0 = (f32x16)(0.f);
            f32x16 acc1 = (f32x16)(0.f);
            #pragma unroll
            for (int ks = 0; ks < 8; ++ks) {
                acc0 = __builtin_amdgcn_mfma_f32_32x32x16_bf16(
                    afrag[0][ks], bfrag[ks], acc0, 0, 0, 0);
                acc1 = __builtin_amdgcn_mfma_f32_32x32x16_bf16(
                    afrag[1][ks], bfrag[ks], acc1, 0, 0, 0);
            }

            // ---- reduce: max over valid rows (hw), sum over 32 cols (l) ----
            // C/D (m74/m101): col = lane&31, row r = (reg&3)+8*(reg>>2)+4*h
            // acc0: m = r (all 32 valid). acc1: m = 32+r, valid iff r <= 16:
            //   regs 0..7 always; reg 8 (r=16) only for h==0.
            float cm = acc0[0];
            #pragma unroll
            for (int r = 1; r < 16; ++r) cm = fmaxf(cm, acc0[r]);
            #pragma unroll
            for (int r = 0; r < 8; ++r)  cm = fmaxf(cm, acc1[r]);
            if (h == 0) cm = fmaxf(cm, acc1[8]);

            cm = fmaxf(cm, __shfl_xor(cm, 32));   // merge k-halves (rows)
            float s = cm;                          // col = ml
            s += __shfl_xor(s, 1);
            s += __shfl_xor(s, 2);
            s += __shfl_xor(s, 4);
            s += __shfl_xor(s, 8);
            s += __shfl_xor(s, 16);                // sum over 32 cols
            if (lane == 0) {
                float v = s * rl;
                out[img_i * NT + t] = v;             // logits_per_image[i,t]
                out[NI * NT + t * NI + img_i] = v;   // logits_per_text[t,i]
            }
        }
    }
}

extern "C" void kernel_launch(void* const* d_in, const int* in_sizes, int n_in,
                              void* d_out, int out_size, void* d_ws, size_t ws_size,
                              hipStream_t stream)
{
    const float* img  = (const float*)d_in[0];
    const float* txt  = (const float*)d_in[1];
    const int*   tlen = (const int*)d_in[2];
    const float* nlt  = (const float*)d_in[3];
    float* out = (float*)d_out;
    clip_match_kernel<<<dim3(1024), dim3(256), 0, stream>>>(img, txt, tlen, nlt, out);
}